// Round 16
// baseline (339.481 us; speedup 1.0000x reference)
//
#include <hip/hip_runtime.h>
#include <math.h>
#include <stdint.h>

#define NPTS 4096
#define KMAX 300
#define SORT_N 512
#define NTHR 256
#define PERTHR 16            // NPTS / NTHR
#define NFEAT 336            // features kept for ranks < NFEAT
#define TIE_TOL 4u           // full-bits ulp window: "reference order unknowable"
#define NBIN 4096            // stage-1 histogram on bits>>20
#define NBKT 64              // rank buckets anchored at the cut

typedef unsigned long long u64;

__device__ __forceinline__ uint32_t bucket_of(uint32_t code12, uint32_t sel1) {
    uint32_t d = (code12 >= sel1) ? 0u : (sel1 - code12);
    if (d > NBKT - 1) d = NBKT - 1;
    return (uint32_t)(NBKT - 1) - d;     // monotone nondecreasing in code12
}

// atan2(x,y)/pi for x >= 0, result in [0,1]. Max err ~3e-6 (A&S 4.4.48 / pi).
__device__ __forceinline__ float atan2pi_pos(float x, float y) {
    float ay = fabsf(y);
    float mx = fmaxf(x, ay);
    float mn = fminf(x, ay);
    float t = mn * __builtin_amdgcn_rcpf(fmaxf(mx, 1e-38f));
    float s = t * t;
    float p = t * (0.3182663f + s * (-0.1051373f + s * (0.0573400f +
                   s * (-0.0270980f + s * 0.0066320f))));
    p = (x > ay) ? (0.5f - p) : p;
    return (y < 0.0f) ? (1.0f - p) : p;
}

__global__ __launch_bounds__(NTHR) void ppf_kernel(
    const float* __restrict__ pts,
    const float* __restrict__ nrm,
    float* __restrict__ out)
{
    const int row = blockIdx.x;          // b*4096 + i
    const int b = row >> 12;
    const int i = row & (NPTS - 1);
    const int t = threadIdx.x;

    // s_buf (16 KB) phases:
    //  A: uint32 hist[4096] (16 KB)
    //  B/C: ktmp u64[512] @0 | ksort u64[512] @4K | feat[336][4] @8K (5.25 KB)
    __shared__ __align__(16) unsigned char s_buf[NBIN * 4];
    uint32_t* s_hist = (uint32_t*)s_buf;
    u64* s_ktmp = (u64*)s_buf;
    u64* s_ksort = (u64*)(s_buf + 4096);
    float (*s_feat)[4] = (float(*)[4])(s_buf + 8192);
    __shared__ uint32_t s_gsum[NTHR];    // stage-1 16-bin group sums
    __shared__ uint32_t s_h2[NTHR];      // stage-2 256-bin hist
    __shared__ uint32_t s_s4[64];        // wave-0 4-group partial sums
    __shared__ uint32_t s_bcnt[NBKT];
    __shared__ uint32_t s_pfx[NBKT];
    __shared__ uint32_t s_cur[NBKT];
    __shared__ uint32_t s_sel;           // stage1: sel1; stage2: 20-bit prefix P
    __shared__ uint32_t s_below;
    __shared__ uint32_t s_M;

    const float* ptsB = pts + (size_t)b * NPTS * 3;
    const float* nrmB = nrm + (size_t)b * NPTS * 3;

    const float pix = ptsB[3*i], piy = ptsB[3*i+1], piz = ptsB[3*i+2];
    const float nix = nrmB[3*i], niy = nrmB[3*i+1], niz = nrmB[3*i+2];
    float sqi;
    {
#pragma clang fp contract(off)
        sqi = pix*pix + piy*piy + piz*piz;
    }

    // ---- A0: zero stage-1 histogram (vectorized) ----
    {
        uint4* H4 = (uint4*)s_hist;
#pragma unroll
        for (int q = 0; q < 4; ++q) H4[q * NTHR + t] = make_uint4(0u, 0u, 0u, 0u);
    }
    __syncthreads();                                          // #1

    // ---- A1: d2 bits for own contiguous 16 points (float4 loads, immediate offsets).
    //      d2 arithmetic bit-identical to R15 (sequential, no fma, fmax 0). ----
    uint32_t bits[PERTHR];
    {
        const float4* P4 = (const float4*)(ptsB) + t * 12;    // 48 floats/thread
#pragma unroll
        for (int c = 0; c < 4; ++c) {
            float4 v0 = P4[c*3 + 0];
            float4 v1 = P4[c*3 + 1];
            float4 v2 = P4[c*3 + 2];
            float px[4], py[4], pz[4];
            px[0] = v0.x; py[0] = v0.y; pz[0] = v0.z;
            px[1] = v0.w; py[1] = v1.x; pz[1] = v1.y;
            px[2] = v1.z; py[2] = v1.w; pz[2] = v2.x;
            px[3] = v2.y; py[3] = v2.z; pz[3] = v2.w;
#pragma unroll
            for (int u = 0; u < 4; ++u) {
#pragma clang fp contract(off)
                float xj = px[u], yj = py[u], zj = pz[u];
                float sqj = xj*xj + yj*yj + zj*zj;
                float dot = pix*xj + piy*yj + piz*zj;
                float d2 = sqi + sqj - 2.0f*dot;
                d2 = fmaxf(d2, 0.0f);
                bits[c*4 + u] = __float_as_uint(d2);
            }
        }
    }
#pragma unroll
    for (int q = 0; q < PERTHR; ++q)
        atomicAdd(&s_hist[bits[q] >> 20], 1u);
    __syncthreads();                                          // #2

    // ---- A2: per-thread 16-bin group sums (vectorized); zero stage-2 + buckets ----
    {
        const uint4* H4 = (const uint4*)s_hist;
        uint32_t gs = 0;
#pragma unroll
        for (int q = 0; q < 4; ++q) {
            uint4 v = H4[t*4 + q];
            gs += v.x + v.y + v.z + v.w;
        }
        s_gsum[t] = gs;
    }
    s_h2[t] = 0;
    if (t < NBKT) s_bcnt[t] = 0;
    __syncthreads();                                          // #3

    // ---- A3 (wave 0): in-wave broadcast prefix; cut-owning lane refines sel1/below ----
    if (t < 64) {
        uint32_t s4 = s_gsum[4*t] + s_gsum[4*t+1] + s_gsum[4*t+2] + s_gsum[4*t+3];
        s_s4[t] = s4;
        uint32_t pfx = 0;
#pragma unroll
        for (int q = 0; q < 64; ++q) {
            uint32_t c = s_s4[q];                 // broadcast read, in-wave ordered
            pfx += (q < t) ? c : 0u;
        }
        if (pfx < KMAX && pfx + s4 >= KMAX) {     // exactly one lane
            uint32_t a = pfx, selbin = 0, below = 0;
            for (int g = 4*t; g < 4*t + 4; ++g) {
                uint32_t gs = s_gsum[g];
                if (a + gs >= KMAX) {
                    for (int q = 0; q < 16; ++q) {
                        uint32_t c = s_hist[g*16 + q];
                        if (a + c >= KMAX) { selbin = (uint32_t)(g*16 + q); below = a; break; }
                        a += c;
                    }
                    break;
                }
                a += gs;
            }
            s_sel = selbin;
            s_below = below;
        }
    }
    __syncthreads();                                          // #4
    const uint32_t sel1 = s_sel;

    // ---- A4: stage-2 hist (256 bins on bits[19:12], restricted to bin sel1) ----
#pragma unroll
    for (int q = 0; q < PERTHR; ++q) {
        if ((bits[q] >> 20) == sel1)
            atomicAdd(&s_h2[(bits[q] >> 12) & 255u], 1u);
    }
    __syncthreads();                                          // #5

    // ---- A5 (wave 0): parallel scan of stage-2 hist -> exact 20-bit prefix P ----
    if (t < 64) {
        uint32_t k2 = KMAX - s_below;             // >= 1
        uint32_t s4 = s_h2[4*t] + s_h2[4*t+1] + s_h2[4*t+2] + s_h2[4*t+3];
        s_s4[t] = s4;
        uint32_t pfx = 0;
#pragma unroll
        for (int q = 0; q < 64; ++q) {
            uint32_t c = s_s4[q];
            pfx += (q < t) ? c : 0u;
        }
        if (pfx < k2 && pfx + s4 >= k2) {         // exactly one lane
            uint32_t a = pfx, s2 = (uint32_t)(4*t);
            for (int q2 = 4*t; q2 < 4*t + 4; ++q2) {
                uint32_t c = s_h2[q2];
                if (a + c >= k2) { s2 = (uint32_t)q2; break; }
                a += c;
            }
            s_sel = (sel1 << 8) | s2;
        }
    }
    __syncthreads();                                          // #6
    const uint32_t P = s_sel;

    // ---- B1: count candidates per bucket ----
#pragma unroll
    for (int q = 0; q < PERTHR; ++q) {
        if ((bits[q] >> 12) <= P + 1)
            atomicAdd(&s_bcnt[bucket_of(bits[q] >> 20, sel1)], 1u);
    }
    __syncthreads();                                          // #7

    // ---- B2: 64-lane broadcast prefix over buckets ----
    if (t < NBKT) {
        uint32_t pfx = 0;
#pragma unroll
        for (int q = 0; q < NBKT; ++q) {
            uint32_t c = s_bcnt[q];
            pfx += (q < t) ? c : 0u;
        }
        s_pfx[t] = pfx;
        s_cur[t] = pfx;
        if (t == NBKT - 1) s_M = pfx + s_bcnt[NBKT - 1];
    }
    __syncthreads();                                          // #8

    // ---- B3: cursor-claim scatter into contiguous buckets ----
#pragma unroll
    for (int q = 0; q < PERTHR; ++q) {
        if ((bits[q] >> 12) <= P + 1) {
            uint32_t bk = bucket_of(bits[q] >> 20, sel1);
            uint32_t s = atomicAdd(&s_cur[bk], 1u);
            if (s < SORT_N) {
                int j = t * PERTHR + q;           // contiguous mapping
                s_ktmp[s] = ((u64)bits[q] << 32) | (uint32_t)j;
            }
        }
    }
    __syncthreads();                                          // #9
    const int M = (int)((s_M < (uint32_t)SORT_N) ? s_M : (uint32_t)SORT_N);
    const int T = (M < NFEAT) ? M : NFEAT;

    // ---- B4: rank within own bucket (dense reads); write sorted (distinct array) ----
#pragma unroll
    for (int e = 0; e < 2; ++e) {
        int s = t + e * NTHR;
        if (s < M) {
            u64 kk = s_ktmp[s];
            uint32_t bk = bucket_of((uint32_t)(kk >> 52), sel1);
            int lo = (int)s_pfx[bk];
            int hi = lo + (int)s_bcnt[bk];
            if (hi > M) hi = M;
            int cnt = 0;
            for (int r = lo; r < hi; ++r)
                cnt += (s_ktmp[r] < kk);
            int rank = lo + cnt;
            if (rank < SORT_N) s_ksort[rank] = kk;
        }
    }
    __syncthreads();                                          // #10

    // ---- C1: PPF features dense by rank (polynomial atan2pi; feature-accuracy path) ----
#pragma unroll
    for (int e = 0; e < 2; ++e) {
        int r = t + e * NTHR;
        if (r < T) {
            u64 kk = s_ksort[r];
            int j = (int)(uint32_t)(kk & 0xFFFFFFFFull);
            float xj = ptsB[3*j], yj = ptsB[3*j+1], zj = ptsB[3*j+2];
            float mx = nrmB[3*j], my = nrmB[3*j+1], mz = nrmB[3*j+2];
            float dx = xj - pix, dy = yj - piy, dz = zj - piz;
            float d = sqrtf(dx*dx + dy*dy + dz*dz);

            float y1 = nix*dx + niy*dy + niz*dz;
            float c1x = niy*dz - niz*dy, c1y = niz*dx - nix*dz, c1z = nix*dy - niy*dx;
            float x1 = sqrtf(c1x*c1x + c1y*c1y + c1z*c1z);
            float a1 = atan2pi_pos(x1, y1);

            float y2 = mx*dx + my*dy + mz*dz;
            float c2x = my*dz - mz*dy, c2y = mz*dx - mx*dz, c2z = mx*dy - my*dx;
            float x2 = sqrtf(c2x*c2x + c2y*c2y + c2z*c2z);
            float a2 = atan2pi_pos(x2, y2);

            float y3 = nix*mx + niy*my + niz*mz;
            float c3x = niy*mz - niz*my, c3y = niz*mx - nix*mz, c3z = nix*my - niy*mx;
            float x3 = sqrtf(c3x*c3x + c3y*c3y + c3z*c3z);
            float a3 = atan2pi_pos(x3, y3);

            // self-point: reference reductions init accumulator with +0.0 ->
            // y = +0 regardless of signed-zero products -> arctan2(+0,+0)=0.
            if (j == i) { d = 0.0f; a1 = 0.0f; a2 = 0.0f; }

            s_feat[r][0] = d; s_feat[r][1] = a1; s_feat[r][2] = a2; s_feat[r][3] = a3;
        }
    }
    __syncthreads();                                          // #11

    // ---- C2: band means with tie-run smoothing at boundaries (identical to R15) ----
    if (t < 24) {
        const int band = t >> 2, f = t & 3;
        const int lo = (band == 0) ? 0 : (10 << (band - 1));
        const int hi = (band == 5) ? 300 : (10 << band);

        float sum = 0.f;
        int mid_lo = lo;
        int mid_hi = (hi < T) ? hi : T;

        #define BITS(r) ((uint32_t)(s_ksort[(r)] >> 32))
        #define CHAINED(r) (BITS(r) - BITS((r)-1) <= TIE_TOL)

        if (lo > 0 && lo < T && CHAINED(lo)) {
            int a = lo - 1; while (a > 0 && CHAINED(a)) --a;
            int bq = lo;    while (bq + 1 < T && CHAINED(bq + 1)) ++bq;
            float w = (float)(bq + 1 - lo) / (float)(bq + 1 - a);
            for (int r = a; r <= bq; ++r) sum += w * s_feat[r][f];
            mid_lo = bq + 1;
        }
        if (hi < T && CHAINED(hi)) {
            int a = hi - 1; while (a > 0 && CHAINED(a)) --a;
            int bq = hi;    while (bq + 1 < T && CHAINED(bq + 1)) ++bq;
            float w = (float)(hi - a) / (float)(bq + 1 - a);
            for (int r = a; r <= bq; ++r) sum += w * s_feat[r][f];
            mid_hi = a;
        }
        #undef BITS
        #undef CHAINED

        for (int r = mid_lo; r < mid_hi; ++r) sum += s_feat[r][f];
        out[(size_t)row * 24 + band * 4 + f] = sum / (float)(hi - lo);
    }
}

extern "C" void kernel_launch(void* const* d_in, const int* in_sizes, int n_in,
                              void* d_out, int out_size, void* d_ws, size_t ws_size,
                              hipStream_t stream) {
    (void)n_in; (void)out_size; (void)d_ws; (void)ws_size;
    const float* pts = (const float*)d_in[0];
    const float* nrm = (const float*)d_in[1];
    float* out = (float*)d_out;
    const int rows = in_sizes[0] / 3;   // b * n = 32768
    ppf_kernel<<<dim3(rows), dim3(NTHR), 0, stream>>>(pts, nrm, out);
}

// Round 17
// 315.232 us; speedup vs baseline: 1.0769x; 1.0769x over previous
//
#include <hip/hip_runtime.h>
#include <math.h>
#include <stdint.h>

#define NPTS 4096
#define KMAX 300
#define SORT_N 512
#define NTHR 256
#define PERTHR 16            // NPTS / NTHR
#define NFEAT 336            // features kept for ranks < NFEAT
#define TIE_TOL 4u           // full-bits ulp window: "reference order unknowable"
#define NBIN 2048            // stage-1 histogram on bits>>21 (8 KB)
#define NBKT 64              // rank buckets anchored at the cut (12-bit codes)

typedef unsigned long long u64;

__device__ __forceinline__ uint32_t bucket_of(uint32_t code12, uint32_t sel12) {
    uint32_t d = (code12 >= sel12) ? 0u : (sel12 - code12);
    if (d > NBKT - 1) d = NBKT - 1;
    return (uint32_t)(NBKT - 1) - d;     // monotone nondecreasing in code12
}

// atan2(x,y)/pi for x >= 0, result in [0,1]. Max err ~3e-6.
__device__ __forceinline__ float atan2pi_pos(float x, float y) {
    float ay = fabsf(y);
    float mx = fmaxf(x, ay);
    float mn = fminf(x, ay);
    float t = mn * __builtin_amdgcn_rcpf(fmaxf(mx, 1e-38f));
    float s = t * t;
    float p = t * (0.3182663f + s * (-0.1051373f + s * (0.0573400f +
                   s * (-0.0270980f + s * 0.0066320f))));
    p = (x > ay) ? (0.5f - p) : p;
    return (y < 0.0f) ? (1.0f - p) : p;
}

__global__ __launch_bounds__(NTHR) void ppf_kernel(
    const float* __restrict__ pts,
    const float* __restrict__ nrm,
    float* __restrict__ out)
{
    const int row = blockIdx.x;          // b*4096 + i
    const int b = row >> 12;
    const int i = row & (NPTS - 1);
    const int t = threadIdx.x;

    // s_buf (13568 B) phases:
    //  A: uint32 hist[2048] @0 (8 KB)
    //  B/C: ktmp u64[512] @0 | ksort u64[512] @4K | feat[336][4] @8K (5.25 KB)
    __shared__ __align__(16) unsigned char s_buf[13568];
    uint32_t* s_hist = (uint32_t*)s_buf;
    u64* s_ktmp = (u64*)s_buf;
    u64* s_ksort = (u64*)(s_buf + 4096);
    float (*s_feat)[4] = (float(*)[4])(s_buf + 8192);
    __shared__ uint32_t s_gsum[NTHR];    // stage-1 8-bin group sums
    __shared__ uint32_t s_h2[NTHR];      // stage-2 256-bin hist
    __shared__ uint32_t s_s4[64];        // wave-0 4-group partial sums
    __shared__ uint32_t s_bcnt[NBKT];
    __shared__ uint32_t s_pfx[NBKT];
    __shared__ uint32_t s_cur[NBKT];
    __shared__ uint32_t s_sel;           // stage1: sel1 (11-bit); stage2: P19
    __shared__ uint32_t s_below;
    __shared__ uint32_t s_M;

    const float* ptsB = pts + (size_t)b * NPTS * 3;
    const float* nrmB = nrm + (size_t)b * NPTS * 3;

    const float pix = ptsB[3*i], piy = ptsB[3*i+1], piz = ptsB[3*i+2];
    const float nix = nrmB[3*i], niy = nrmB[3*i+1], niz = nrmB[3*i+2];
    float sqi;
    {
#pragma clang fp contract(off)
        sqi = pix*pix + piy*piy + piz*piz;
    }

    // ---- A0: zero stage-1 histogram (8 KB, vectorized) ----
    {
        uint4* H4 = (uint4*)s_hist;
#pragma unroll
        for (int q = 0; q < 2; ++q) H4[q * NTHR + t] = make_uint4(0u, 0u, 0u, 0u);
    }
    __syncthreads();                                          // #1

    // ---- A1: d2 bits for own contiguous 16 points (float4 loads).
    //      d2 arithmetic bit-identical (sequential, no fma, fmax 0). ----
    uint32_t bits[PERTHR];
    {
        const float4* P4 = (const float4*)(ptsB) + t * 12;    // 48 floats/thread
#pragma unroll
        for (int c = 0; c < 4; ++c) {
            float4 v0 = P4[c*3 + 0];
            float4 v1 = P4[c*3 + 1];
            float4 v2 = P4[c*3 + 2];
            float px[4], py[4], pz[4];
            px[0] = v0.x; py[0] = v0.y; pz[0] = v0.z;
            px[1] = v0.w; py[1] = v1.x; pz[1] = v1.y;
            px[2] = v1.z; py[2] = v1.w; pz[2] = v2.x;
            px[3] = v2.y; py[3] = v2.z; pz[3] = v2.w;
#pragma unroll
            for (int u = 0; u < 4; ++u) {
#pragma clang fp contract(off)
                float xj = px[u], yj = py[u], zj = pz[u];
                float sqj = xj*xj + yj*yj + zj*zj;
                float dot = pix*xj + piy*yj + piz*zj;
                float d2 = sqi + sqj - 2.0f*dot;
                d2 = fmaxf(d2, 0.0f);
                bits[c*4 + u] = __float_as_uint(d2);
            }
        }
    }
#pragma unroll
    for (int q = 0; q < PERTHR; ++q)
        atomicAdd(&s_hist[bits[q] >> 21], 1u);
    __syncthreads();                                          // #2

    // ---- A2: per-thread 8-bin group sums; zero stage-2 + buckets ----
    {
        const uint4* H4 = (const uint4*)s_hist;
        uint4 v0 = H4[t*2], v1 = H4[t*2 + 1];
        s_gsum[t] = v0.x + v0.y + v0.z + v0.w + v1.x + v1.y + v1.z + v1.w;
    }
    s_h2[t] = 0;
    if (t < NBKT) s_bcnt[t] = 0;
    __syncthreads();                                          // #3

    // ---- A3 (wave 0): in-wave broadcast prefix; cut-owning lane refines sel1/below ----
    if (t < 64) {
        uint32_t s4 = s_gsum[4*t] + s_gsum[4*t+1] + s_gsum[4*t+2] + s_gsum[4*t+3];
        s_s4[t] = s4;
        uint32_t pfx = 0;
#pragma unroll
        for (int q = 0; q < 64; ++q) {
            uint32_t c = s_s4[q];                 // broadcast read, in-wave ordered
            pfx += (q < t) ? c : 0u;
        }
        if (pfx < KMAX && pfx + s4 >= KMAX) {     // exactly one lane
            uint32_t a = pfx, selbin = 0, below = 0;
            for (int g = 4*t; g < 4*t + 4; ++g) {
                uint32_t gs = s_gsum[g];
                if (a + gs >= KMAX) {
                    for (int q = 0; q < 8; ++q) {
                        uint32_t c = s_hist[g*8 + q];
                        if (a + c >= KMAX) { selbin = (uint32_t)(g*8 + q); below = a; break; }
                        a += c;
                    }
                    break;
                }
                a += gs;
            }
            s_sel = selbin;
            s_below = below;
        }
    }
    __syncthreads();                                          // #4
    const uint32_t sel1 = s_sel;                 // 11-bit bin of rank KMAX

    // ---- A4: stage-2 hist (256 bins on bits[20:13], restricted to bin sel1) ----
#pragma unroll
    for (int q = 0; q < PERTHR; ++q) {
        if ((bits[q] >> 21) == sel1)
            atomicAdd(&s_h2[(bits[q] >> 13) & 255u], 1u);
    }
    __syncthreads();                                          // #5

    // ---- A5 (wave 0): parallel scan of stage-2 hist -> exact 19-bit prefix P19 ----
    if (t < 64) {
        uint32_t k2 = KMAX - s_below;             // >= 1
        uint32_t s4 = s_h2[4*t] + s_h2[4*t+1] + s_h2[4*t+2] + s_h2[4*t+3];
        s_s4[t] = s4;
        uint32_t pfx = 0;
#pragma unroll
        for (int q = 0; q < 64; ++q) {
            uint32_t c = s_s4[q];
            pfx += (q < t) ? c : 0u;
        }
        if (pfx < k2 && pfx + s4 >= k2) {         // exactly one lane
            uint32_t a = pfx, s2 = (uint32_t)(4*t);
            for (int q2 = 4*t; q2 < 4*t + 4; ++q2) {
                uint32_t c = s_h2[q2];
                if (a + c >= k2) { s2 = (uint32_t)q2; break; }
                a += c;
            }
            s_sel = (sel1 << 8) | s2;
        }
    }
    __syncthreads();                                          // #6
    const uint32_t P19 = s_sel;
    const uint32_t sel12 = P19 >> 7;             // 12-bit code of the cut

    // ---- B1: count candidates per bucket ----
#pragma unroll
    for (int q = 0; q < PERTHR; ++q) {
        if ((bits[q] >> 13) <= P19 + 1)
            atomicAdd(&s_bcnt[bucket_of(bits[q] >> 20, sel12)], 1u);
    }
    __syncthreads();                                          // #7

    // ---- B2: 64-lane broadcast prefix over buckets ----
    if (t < NBKT) {
        uint32_t pfx = 0;
#pragma unroll
        for (int q = 0; q < NBKT; ++q) {
            uint32_t c = s_bcnt[q];
            pfx += (q < t) ? c : 0u;
        }
        s_pfx[t] = pfx;
        s_cur[t] = pfx;
        if (t == NBKT - 1) s_M = pfx + s_bcnt[NBKT - 1];
    }
    __syncthreads();                                          // #8

    // ---- B3: cursor-claim scatter into contiguous buckets ----
#pragma unroll
    for (int q = 0; q < PERTHR; ++q) {
        if ((bits[q] >> 13) <= P19 + 1) {
            uint32_t bk = bucket_of(bits[q] >> 20, sel12);
            uint32_t s = atomicAdd(&s_cur[bk], 1u);
            if (s < SORT_N) {
                int j = t * PERTHR + q;           // contiguous mapping
                s_ktmp[s] = ((u64)bits[q] << 32) | (uint32_t)j;
            }
        }
    }
    __syncthreads();                                          // #9
    const int M = (int)((s_M < (uint32_t)SORT_N) ? s_M : (uint32_t)SORT_N);
    const int T = (M < NFEAT) ? M : NFEAT;

    // ---- B4+C1 merged: rank within own bucket, then compute features directly
    //      (j already in register); write ksort (for C2 ties) + feat[rank] ----
#pragma unroll
    for (int e = 0; e < 2; ++e) {
        int s = t + e * NTHR;
        if (s < M) {
            u64 kk = s_ktmp[s];
            uint32_t bk = bucket_of((uint32_t)(kk >> 52), sel12);
            int lo = (int)s_pfx[bk];
            int hi = lo + (int)s_bcnt[bk];
            if (hi > M) hi = M;
            int cnt = 0;
            for (int r = lo; r < hi; ++r)
                cnt += (s_ktmp[r] < kk);
            int rank = lo + cnt;
            if (rank < SORT_N) s_ksort[rank] = kk;

            if (rank < T) {
                int j = (int)(uint32_t)(kk & 0xFFFFFFFFull);
                float xj = ptsB[3*j], yj = ptsB[3*j+1], zj = ptsB[3*j+2];
                float mx = nrmB[3*j], my = nrmB[3*j+1], mz = nrmB[3*j+2];
                float dx = xj - pix, dy = yj - piy, dz = zj - piz;
                float d = sqrtf(dx*dx + dy*dy + dz*dz);

                float y1 = nix*dx + niy*dy + niz*dz;
                float c1x = niy*dz - niz*dy, c1y = niz*dx - nix*dz, c1z = nix*dy - niy*dx;
                float x1 = sqrtf(c1x*c1x + c1y*c1y + c1z*c1z);
                float a1 = atan2pi_pos(x1, y1);

                float y2 = mx*dx + my*dy + mz*dz;
                float c2x = my*dz - mz*dy, c2y = mz*dx - mx*dz, c2z = mx*dy - my*dx;
                float x2 = sqrtf(c2x*c2x + c2y*c2y + c2z*c2z);
                float a2 = atan2pi_pos(x2, y2);

                float y3 = nix*mx + niy*my + niz*mz;
                float c3x = niy*mz - niz*my, c3y = niz*mx - nix*mz, c3z = nix*my - niy*mx;
                float x3 = sqrtf(c3x*c3x + c3y*c3y + c3z*c3z);
                float a3 = atan2pi_pos(x3, y3);

                // self-point: reference reductions init accumulator with +0.0 ->
                // y = +0 regardless of signed-zero products -> arctan2(+0,+0)=0.
                if (j == i) { d = 0.0f; a1 = 0.0f; a2 = 0.0f; }

                s_feat[rank][0] = d; s_feat[rank][1] = a1;
                s_feat[rank][2] = a2; s_feat[rank][3] = a3;
            }
        }
    }
    __syncthreads();                                          // #10

    // ---- C2: band means with tie-run smoothing at boundaries (identical) ----
    if (t < 24) {
        const int band = t >> 2, f = t & 3;
        const int lo = (band == 0) ? 0 : (10 << (band - 1));
        const int hi = (band == 5) ? 300 : (10 << band);

        float sum = 0.f;
        int mid_lo = lo;
        int mid_hi = (hi < T) ? hi : T;

        #define BITS(r) ((uint32_t)(s_ksort[(r)] >> 32))
        #define CHAINED(r) (BITS(r) - BITS((r)-1) <= TIE_TOL)

        if (lo > 0 && lo < T && CHAINED(lo)) {
            int a = lo - 1; while (a > 0 && CHAINED(a)) --a;
            int bq = lo;    while (bq + 1 < T && CHAINED(bq + 1)) ++bq;
            float w = (float)(bq + 1 - lo) / (float)(bq + 1 - a);
            for (int r = a; r <= bq; ++r) sum += w * s_feat[r][f];
            mid_lo = bq + 1;
        }
        if (hi < T && CHAINED(hi)) {
            int a = hi - 1; while (a > 0 && CHAINED(a)) --a;
            int bq = hi;    while (bq + 1 < T && CHAINED(bq + 1)) ++bq;
            float w = (float)(hi - a) / (float)(bq + 1 - a);
            for (int r = a; r <= bq; ++r) sum += w * s_feat[r][f];
            mid_hi = a;
        }
        #undef BITS
        #undef CHAINED

        for (int r = mid_lo; r < mid_hi; ++r) sum += s_feat[r][f];
        out[(size_t)row * 24 + band * 4 + f] = sum / (float)(hi - lo);
    }
}

extern "C" void kernel_launch(void* const* d_in, const int* in_sizes, int n_in,
                              void* d_out, int out_size, void* d_ws, size_t ws_size,
                              hipStream_t stream) {
    (void)n_in; (void)out_size; (void)d_ws; (void)ws_size;
    const float* pts = (const float*)d_in[0];
    const float* nrm = (const float*)d_in[1];
    float* out = (float*)d_out;
    const int rows = in_sizes[0] / 3;   // b * n = 32768
    ppf_kernel<<<dim3(rows), dim3(NTHR), 0, stream>>>(pts, nrm, out);
}